// Round 1
// baseline (114.991 us; speedup 1.0000x reference)
//
#include <hip/hip_runtime.h>

typedef float f4v __attribute__((ext_vector_type(4), aligned(4)));
typedef float f2v __attribute__((ext_vector_type(2), aligned(8)));

__device__ __forceinline__ float fast_tanh(float x) {
  // tanh(x) = 1 - 2/(1 + exp2(x * 2*log2(e)))
  float t = x * 2.8853900817779268f;
#if __has_builtin(__builtin_amdgcn_exp2f)
  float e = __builtin_amdgcn_exp2f(t);
#else
  float e = exp2f(t);
#endif
#if __has_builtin(__builtin_amdgcn_rcpf)
  float r = __builtin_amdgcn_rcpf(e + 1.0f);
#else
  float r = 1.0f / (e + 1.0f);
#endif
  return 1.0f - 2.0f * r;
}

__device__ __forceinline__ void loadrow(const float* __restrict__ xs, int row,
                                        float* __restrict__ d0,
                                        float* __restrict__ d1) {
  // load cols 0..19 of `row` for both channels (ch stride 273 floats)
  const f4v* p0 = reinterpret_cast<const f4v*>(xs + row * 21);
  const f4v* p1 = reinterpret_cast<const f4v*>(xs + 273 + row * 21);
#pragma unroll
  for (int k = 0; k < 5; ++k) {
    f4v a = p0[k];
    f4v b = p1[k];
#pragma unroll
    for (int l = 0; l < 4; ++l) {
      d0[4 * k + l] = a[l];
      d1[4 * k + l] = b[l];
    }
  }
}

__global__ __launch_bounds__(256, 2) void smartpixel_kernel(
    const float* __restrict__ x, const float* __restrict__ dw_w,
    const float* __restrict__ pw_w, const float* __restrict__ pw_b,
    const float* __restrict__ conv_w, const float* __restrict__ conv_b,
    const float* __restrict__ w1, const float* __restrict__ b1,
    const float* __restrict__ w2, const float* __restrict__ b2,
    const float* __restrict__ w3, const float* __restrict__ b3,
    float* __restrict__ out, int nsamp) {
  const int s = blockIdx.x * 256 + threadIdx.x;
  if (s >= nsamp) return;
  const float* xs = x + (long)s * 546;

  float w0r[3][20], w1r[3][20];   // rolling window, ch0/ch1, rows i..i+2
  float pf0[20], pf1[20];         // prefetch buffer (row i+3)

  // preload rows 0,1 into slots 1,2; row 2 into prefetch
  loadrow(xs, 0, w0r[1], w1r[1]);
  loadrow(xs, 1, w0r[2], w1r[2]);
  loadrow(xs, 2, pf0, pf1);

  float pool[5][6];
#pragma unroll
  for (int c = 0; c < 5; ++c)
#pragma unroll
    for (int j = 0; j < 6; ++j) pool[c][j] = 0.0f;

  float h1a[16];
#pragma unroll
  for (int o = 0; o < 16; ++o) h1a[o] = b1[o];

#pragma unroll 1
  for (int i = 0; i < 9; ++i) {
    // shift window down one row; bring in prefetched row
#pragma unroll
    for (int k = 0; k < 20; ++k) {
      w0r[0][k] = w0r[1][k]; w0r[1][k] = w0r[2][k]; w0r[2][k] = pf0[k];
      w1r[0][k] = w1r[1][k]; w1r[1][k] = w1r[2][k]; w1r[2][k] = pf1[k];
    }
    // prefetch row i+3 (clamped: last iterations re-load row 10, cache-hot)
    int lr = i + 3; if (lr > 10) lr = 10;
    loadrow(xs, lr, pf0, pf1);

#pragma unroll
    for (int j = 0; j < 18; ++j) {
      // depthwise 3x3, both channels
      float d0 = w0r[0][j] * dw_w[0] + w0r[0][j + 1] * dw_w[1] + w0r[0][j + 2] * dw_w[2]
               + w0r[1][j] * dw_w[3] + w0r[1][j + 1] * dw_w[4] + w0r[1][j + 2] * dw_w[5]
               + w0r[2][j] * dw_w[6] + w0r[2][j + 1] * dw_w[7] + w0r[2][j + 2] * dw_w[8];
      float d1 = w1r[0][j] * dw_w[9]  + w1r[0][j + 1] * dw_w[10] + w1r[0][j + 2] * dw_w[11]
               + w1r[1][j] * dw_w[12] + w1r[1][j + 1] * dw_w[13] + w1r[1][j + 2] * dw_w[14]
               + w1r[2][j] * dw_w[15] + w1r[2][j + 1] * dw_w[16] + w1r[2][j + 2] * dw_w[17];
      // pointwise 2->5 + tanh
      float aa[5];
#pragma unroll
      for (int p = 0; p < 5; ++p)
        aa[p] = fast_tanh(pw_b[p] + pw_w[2 * p] * d0 + pw_w[2 * p + 1] * d1);
      // 1x1 5->5 + tanh, accumulate 3x3 pool
#pragma unroll
      for (int q = 0; q < 5; ++q) {
        float acc = conv_b[q];
#pragma unroll
        for (int p = 0; p < 5; ++p) acc += conv_w[5 * q + p] * aa[p];
        pool[q][j / 3] += fast_tanh(acc);
      }
    }

    if ((i % 3) == 2) {  // pool row-group complete: tanh + fc1 accumulation
      int rr = i / 3;
#pragma unroll
      for (int c = 0; c < 5; ++c)
#pragma unroll
        for (int j = 0; j < 6; ++j) {
          float pc = fast_tanh(pool[c][j] * (1.0f / 9.0f));
          pool[c][j] = 0.0f;
          int fidx = c * 18 + rr * 6 + j;
#pragma unroll
          for (int o = 0; o < 16; ++o) h1a[o] += pc * w1[o * 90 + fidx];
        }
    }
  }

  // fc1 tanh
  float h1[16];
#pragma unroll
  for (int k = 0; k < 16; ++k) h1[k] = fast_tanh(h1a[k]);
  // fc2 + tanh
  float h2[16];
#pragma unroll
  for (int o = 0; o < 16; ++o) {
    float acc = b2[o];
#pragma unroll
    for (int k = 0; k < 16; ++k) acc += h1[k] * w2[o * 16 + k];
    h2[o] = fast_tanh(acc);
  }
  // fc3
  float ov[14];
#pragma unroll
  for (int o = 0; o < 14; ++o) {
    float acc = b3[o];
#pragma unroll
    for (int k = 0; k < 16; ++k) acc += h2[k] * w3[o * 16 + k];
    ov[o] = acc;
  }
  // store 14 floats (56B, 8B-aligned) as 7 float2
  f2v* po = reinterpret_cast<f2v*>(out + (long)s * 14);
#pragma unroll
  for (int k = 0; k < 7; ++k) {
    f2v v;
    v[0] = ov[2 * k];
    v[1] = ov[2 * k + 1];
    po[k] = v;
  }
}

extern "C" void kernel_launch(void* const* d_in, const int* in_sizes, int n_in,
                              void* d_out, int out_size, void* d_ws, size_t ws_size,
                              hipStream_t stream) {
  const float* x      = (const float*)d_in[0];
  const float* dw_w   = (const float*)d_in[1];
  const float* pw_w   = (const float*)d_in[2];
  const float* pw_b   = (const float*)d_in[3];
  const float* conv_w = (const float*)d_in[4];
  const float* conv_b = (const float*)d_in[5];
  const float* w1     = (const float*)d_in[6];
  const float* b1     = (const float*)d_in[7];
  const float* w2     = (const float*)d_in[8];
  const float* b2     = (const float*)d_in[9];
  const float* w3     = (const float*)d_in[10];
  const float* b3     = (const float*)d_in[11];
  float* out = (float*)d_out;

  int nsamp = in_sizes[0] / 546;
  int blocks = (nsamp + 255) / 256;
  smartpixel_kernel<<<blocks, 256, 0, stream>>>(
      x, dw_w, pw_w, pw_b, conv_w, conv_b, w1, b1, w2, b2, w3, b3, out, nsamp);
}